// Round 7
// baseline (204.391 us; speedup 1.0000x reference)
//
#include <hip/hip_runtime.h>
#include <math.h>

#define B_DIM 4
#define S_DIM 4096
#define E_DIM 1024
#define A_DIM 64
#define M_TOT (B_DIM * S_DIM) /* 16384 */

typedef __bf16 v8bf __attribute__((ext_vector_type(8)));
typedef __bf16 v4bf __attribute__((ext_vector_type(4)));
typedef float  v4f  __attribute__((ext_vector_type(4)));

__device__ __forceinline__ v4f mfma16(v8bf a, v8bf b, v4f c) {
    return __builtin_amdgcn_mfma_f32_16x16x32_bf16(a, b, c, 0, 0, 0);
}

// ---------------------------------------------------------------------------
// Pre-pass: fp32 weights -> bf16 Wb[192][1024] (rows 0-63 K, 64-127 Q, 128-191 V).
// ---------------------------------------------------------------------------
__global__ __launch_bounds__(256) void wconv_kernel(
    const float* __restrict__ Wk, const float* __restrict__ Wq,
    const float* __restrict__ Wv, __bf16* __restrict__ Wb)
{
    const int i = blockIdx.x * 256 + threadIdx.x;   // float4 index, 49152 total
    const int w = i >> 14;
    const int off = (i & 16383) * 4;
    const float* s = ((w == 0) ? Wk : (w == 1) ? Wq : Wv) + off;
    float4 v = *(const float4*)s;
    v4bf o;
    o[0] = (__bf16)v.x; o[1] = (__bf16)v.y; o[2] = (__bf16)v.z; o[3] = (__bf16)v.w;
    *(v4bf*)(Wb + (size_t)w * 65536 + off) = o;
}

// ---------------------------------------------------------------------------
// Fused QKV projection v5: N-split across waves.
// 1024 blocks x 256 thr; block = 16-row tile x 192 cols, full K=1024.
// Wave w owns cols [48w, 48w+48) = 3 N-tiles -> per kc: 1 A-frag + 3 B-frags
// + 3 MFMAs.  Live frags per stage ~16 regs -> manual 2-stage double buffer
// actually fits (unlike v3/v4's 12-frag versions that spilled/serialized).
// No cross-wave reduction (columns are complete sums).  V cols (128-191,
// waves 2-3) go through a 4.2 KB LDS transpose; one barrier total.
// ---------------------------------------------------------------------------
__global__ __launch_bounds__(256) void qkv_proj_mfma(
    const float* __restrict__ X,
    const __bf16* __restrict__ Wb,   // [192][1024]
    __bf16* __restrict__ Kb,
    __bf16* __restrict__ Qb,
    __bf16* __restrict__ Vt)
{
    const int r0   = blockIdx.x * 16;
    const int w    = threadIdx.x >> 6;
    const int lane = threadIdx.x & 63;
    const int L    = lane & 15;
    const int quad = lane >> 4;
    const int cbase = w * 48;

    __shared__ float Tv[16][66]; // V transpose staging (fp32), 4.2 KB

    v4f acc[3];
#pragma unroll
    for (int nt = 0; nt < 3; ++nt) acc[nt] = (v4f){0.f, 0.f, 0.f, 0.f};

    const int kq = quad * 8;
    const float*  Arow = X + (size_t)(r0 + L) * E_DIM;
    const __bf16* Brow0 = Wb + (size_t)(cbase + 0 * 16 + L) * E_DIM;
    const __bf16* Brow1 = Wb + (size_t)(cbase + 1 * 16 + L) * E_DIM;
    const __bf16* Brow2 = Wb + (size_t)(cbase + 2 * 16 + L) * E_DIM;

    auto loadA = [&](int kc, v8bf& af) {
        const float* p = Arow + kc * 32 + kq;
        float4 a  = *(const float4*)p;
        float4 bq = *(const float4*)(p + 4);
        v8bf f;
        f[0] = (__bf16)a.x;  f[1] = (__bf16)a.y;  f[2] = (__bf16)a.z;  f[3] = (__bf16)a.w;
        f[4] = (__bf16)bq.x; f[5] = (__bf16)bq.y; f[6] = (__bf16)bq.z; f[7] = (__bf16)bq.w;
        af = f;
    };
    auto loadB = [&](int kc, v8bf bfr[3]) {
        const int k0 = kc * 32 + kq;
        bfr[0] = *(const v8bf*)(Brow0 + k0);
        bfr[1] = *(const v8bf*)(Brow1 + k0);
        bfr[2] = *(const v8bf*)(Brow2 + k0);
    };
    auto domfma = [&](v8bf af, v8bf bfr[3]) {
#pragma unroll
        for (int nt = 0; nt < 3; ++nt)
            acc[nt] = mfma16(af, bfr[nt], acc[nt]);
    };

    v8bf af0, bf0[3], af1, bf1[3];
    loadA(0, af0); loadB(0, bf0);
#pragma unroll 1
    for (int kc = 0; kc < 32; kc += 2) {
        loadA(kc + 1, af1); loadB(kc + 1, bf1);
        domfma(af0, bf0);
        if (kc + 2 < 32) { loadA(kc + 2, af0); loadB(kc + 2, bf0); }
        domfma(af1, bf1);
    }

    // write-out: c0 = cbase + nt*16 selects K (<64), Q (<128, x1/8), V (->LDS)
#pragma unroll
    for (int nt = 0; nt < 3; ++nt) {
        const int c0 = cbase + nt * 16; // wave-uniform
        if (c0 < 64) {
#pragma unroll
            for (int r = 0; r < 4; ++r)
                Kb[(size_t)(r0 + quad * 4 + r) * A_DIM + c0 + L] = (__bf16)acc[nt][r];
        } else if (c0 < 128) {
#pragma unroll
            for (int r = 0; r < 4; ++r)
                Qb[(size_t)(r0 + quad * 4 + r) * A_DIM + (c0 - 64) + L] =
                    (__bf16)(acc[nt][r] * 0.125f);
        } else {
#pragma unroll
            for (int r = 0; r < 4; ++r)
                Tv[quad * 4 + r][(c0 - 128) + L] = acc[nt][r];
        }
    }
    __syncthreads();

    // cooperative transposed V write: thread t -> row a = t/4, s-chunk = t%4
    {
        const int batch = r0 >> 12;
        const int s0    = r0 & 4095;
        const int a     = threadIdx.x >> 2;
        const int j4    = threadIdx.x & 3;
        v4bf pk;
#pragma unroll
        for (int j = 0; j < 4; ++j) pk[j] = (__bf16)Tv[j4 * 4 + j][a];
        *(v4bf*)(Vt + (size_t)(batch * 64 + a) * S_DIM + s0 + j4 * 4) = pk;
    }
}

// ---------------------------------------------------------------------------
// Causal flash attention v4 (unchanged): split-K, no-max softmax,
// minimal live registers; acc_o MFMA-only -> AGPRs; Pt wave-private.
// ---------------------------------------------------------------------------
__global__ __launch_bounds__(256, 2) void attn_mfma(
    const __bf16* __restrict__ Qb,
    const __bf16* __restrict__ Kb,
    const __bf16* __restrict__ Vt,
    float* __restrict__ P_l,
    float* __restrict__ P_o,
    float* __restrict__ out)
{
    const int b = blockIdx.y;
    const int x = blockIdx.x;
    int qt, ks;
    if (x < 16)      { qt = x;                    ks = 0; }
    else if (x < 48) { qt = 16 + ((x - 16) >> 1); ks = (x - 16) & 1; }
    else if (x < 96) { int y = x - 48; qt = 32 + y / 3;  ks = y % 3; }
    else             { int y = x - 96; qt = 48 + (y >> 2); ks = y & 3; }
    const int nch = (qt >> 4) + 1;

    const int w    = threadIdx.x >> 6;
    const int lane = threadIdx.x & 63;
    const int L    = lane & 15;
    const int quad = lane >> 4;

    __shared__ __align__(16) char smem[67840];
    __bf16 (*Pt)[64][72]   = (__bf16(*)[64][72])smem;           // loop phase
    float*  red_l          = (float*)smem;                      // combine phase
    float (*red_o)[64][65] = (float(*)[64][65])(smem + 1024);
    float*  invs           = (float*)(smem + 67584);

    v8bf qf[4][2];
#pragma unroll
    for (int ni = 0; ni < 4; ++ni)
#pragma unroll
        for (int ka = 0; ka < 2; ++ka)
            qf[ni][ka] = *(const v8bf*)(Qb +
                (size_t)(b * S_DIM + qt * 64 + ni * 16 + L) * A_DIM + ka * 32 + quad * 8);

    v4f acc_o[4][4];
#pragma unroll
    for (int i = 0; i < 4; ++i)
#pragma unroll
        for (int j = 0; j < 4; ++j) acc_o[i][j] = (v4f){0.f, 0.f, 0.f, 0.f};
    float lrun[4] = {0.f, 0.f, 0.f, 0.f};

    const int kt0   = ks * 16 + w;
    const int ktmax = min(ks * 16 + 15, qt);

    for (int kt = kt0; kt <= ktmax; kt += 4) {
        v8bf kf[4][2];
#pragma unroll
        for (int mi = 0; mi < 4; ++mi)
#pragma unroll
            for (int ka = 0; ka < 2; ++ka)
                kf[mi][ka] = *(const v8bf*)(Kb +
                    (size_t)(b * S_DIM + kt * 64 + mi * 16 + L) * A_DIM + ka * 32 + quad * 8);
        v8bf vf[4][2];
#pragma unroll
        for (int ma = 0; ma < 4; ++ma)
#pragma unroll
            for (int ki = 0; ki < 2; ++ki)
                vf[ma][ki] = *(const v8bf*)(Vt +
                    (size_t)(b * 64 + ma * 16 + L) * S_DIM + kt * 64 + ki * 32 + quad * 8);

        const bool diag = (kt == qt);

#pragma unroll
        for (int ni = 0; ni < 4; ++ni) {
            v4f s[4];
#pragma unroll
            for (int mi = 0; mi < 4; ++mi) s[mi] = (v4f){0.f, 0.f, 0.f, 0.f};
#pragma unroll
            for (int mi = 0; mi < 4; ++mi)
#pragma unroll
                for (int ka = 0; ka < 2; ++ka)
                    s[mi] = mfma16(kf[mi][ka], qf[ni][ka], s[mi]);

            float rs = 0.f;
#pragma unroll
            for (int mi = 0; mi < 4; ++mi) {
                v4bf p4;
#pragma unroll
                for (int r = 0; r < 4; ++r) {
                    const bool masked = diag && (mi * 16 + quad * 4 + r > ni * 16 + L);
                    const float p = masked ? 0.f : __expf(s[mi][r]);
                    rs += p;
                    p4[r] = (__bf16)p;
                }
                *(v4bf*)&Pt[w][ni * 16 + L][mi * 16 + quad * 4] = p4;
            }
            lrun[ni] += rs;
        }

        v8bf pf[4][2];
#pragma unroll
        for (int ni = 0; ni < 4; ++ni)
#pragma unroll
            for (int ki = 0; ki < 2; ++ki)
                pf[ni][ki] = *(const v8bf*)&Pt[w][ni * 16 + L][ki * 32 + quad * 8];
#pragma unroll
        for (int ma = 0; ma < 4; ++ma)
#pragma unroll
            for (int ni = 0; ni < 4; ++ni)
#pragma unroll
                for (int ki = 0; ki < 2; ++ki)
                    acc_o[ma][ni] = mfma16(vf[ma][ki], pf[ni][ki], acc_o[ma][ni]);
    }

#pragma unroll
    for (int ni = 0; ni < 4; ++ni) {
        lrun[ni] += __shfl_xor(lrun[ni], 16, 64);
        lrun[ni] += __shfl_xor(lrun[ni], 32, 64);
    }

    __syncthreads();

    if (quad == 0) {
#pragma unroll
        for (int ni = 0; ni < 4; ++ni)
            red_l[w * 64 + ni * 16 + L] = lrun[ni];
    }
#pragma unroll
    for (int ma = 0; ma < 4; ++ma)
#pragma unroll
        for (int ni = 0; ni < 4; ++ni)
#pragma unroll
            for (int r = 0; r < 4; ++r)
                red_o[w][ma * 16 + quad * 4 + r][ni * 16 + L] = acc_o[ma][ni][r];
    __syncthreads();

    const int pidx = (b * 64 + qt) * 4 + ks;
    if (threadIdx.x < 64) {
        const int q = threadIdx.x;
        const float denom = red_l[0 * 64 + q] + red_l[1 * 64 + q]
                          + red_l[2 * 64 + q] + red_l[3 * 64 + q];
        if (nch == 1) {
            invs[q] = 1.0f / denom;
        } else {
            P_l[(size_t)pidx * 64 + q] = denom;
            invs[q] = 1.0f;
        }
    }
    __syncthreads();

    {
        const int q  = threadIdx.x >> 2;
        const int ac = (threadIdx.x & 3) << 4;
        const float sc = invs[q];
        float* dst = (nch == 1)
            ? out + (size_t)(b * S_DIM + qt * 64 + q) * A_DIM
            : P_o + (size_t)pidx * 4096 + (size_t)q * 64;
#pragma unroll
        for (int i4 = 0; i4 < 4; ++i4) {
            float vv[4];
#pragma unroll
            for (int j = 0; j < 4; ++j) {
                const int a = ac + i4 * 4 + j;
                vv[j] = sc * (red_o[0][a][q] + red_o[1][a][q]
                            + red_o[2][a][q] + red_o[3][a][q]);
            }
            *(float4*)(dst + ac + i4 * 4) = make_float4(vv[0], vv[1], vv[2], vv[3]);
        }
    }
}

// ---------------------------------------------------------------------------
// Combine split-K partials for qt >= 16: out = (sum_c O_c) / (sum_c l_c).
// ---------------------------------------------------------------------------
__global__ __launch_bounds__(256) void attn_combine(
    const float* __restrict__ P_l, const float* __restrict__ P_o,
    float* __restrict__ out)
{
    const int qt  = 16 + blockIdx.x;
    const int b   = blockIdx.y;
    const int nch = (qt >> 4) + 1;
    const int base = (b * 64 + qt) * 4;

    __shared__ float inv_s[64];
    if (threadIdx.x < 64) {
        const int q = threadIdx.x;
        float denom = 0.f;
        for (int c = 0; c < nch; ++c)
            denom += P_l[(size_t)(base + c) * 64 + q];
        inv_s[q] = 1.0f / denom;
    }
    __syncthreads();

    const int q  = threadIdx.x >> 2;
    const int ac = (threadIdx.x & 3) << 4;
    const float inv = inv_s[q];
    float* orow = out + (size_t)(b * S_DIM + qt * 64 + q) * A_DIM;
#pragma unroll
    for (int i4 = 0; i4 < 4; ++i4) {
        float4 acc = make_float4(0.f, 0.f, 0.f, 0.f);
        for (int c = 0; c < nch; ++c) {
            float4 v = *(const float4*)(P_o + (size_t)(base + c) * 4096 +
                                        (size_t)q * 64 + ac + i4 * 4);
            acc.x += v.x; acc.y += v.y; acc.z += v.z; acc.w += v.w;
        }
        acc.x *= inv; acc.y *= inv; acc.z *= inv; acc.w *= inv;
        *(float4*)(orow + ac + i4 * 4) = acc;
    }
}

// ---------------------------------------------------------------------------
extern "C" void kernel_launch(void* const* d_in, const int* in_sizes, int n_in,
                              void* d_out, int out_size, void* d_ws, size_t ws_size,
                              hipStream_t stream)
{
    const float* X  = (const float*)d_in[0];
    const float* Wk = (const float*)d_in[1];
    const float* Wq = (const float*)d_in[2];
    const float* Wv = (const float*)d_in[3];
    float* out = (float*)d_out;

    __bf16* Kb = (__bf16*)d_ws;                     // [16384][64]
    __bf16* Qb = Kb + (size_t)M_TOT * A_DIM;        // [16384][64] (x 1/8)
    __bf16* Vt = Qb + (size_t)M_TOT * A_DIM;        // [256][4096] V^T
    __bf16* Wb = Vt + (size_t)M_TOT * A_DIM;        // [192][1024]
    float*  P_l = (float*)(Wb + 3 * 65536);         // [1024][64]
    float*  P_o = P_l + 65536;                      // [1024][64][64]

    wconv_kernel<<<192, 256, 0, stream>>>(Wk, Wq, Wv, Wb);

    qkv_proj_mfma<<<1024, 256, 0, stream>>>(X, Wb, Kb, Qb, Vt);

    dim3 g2(160, B_DIM), b2(256);
    attn_mfma<<<g2, b2, 0, stream>>>(Qb, Kb, Vt, P_l, P_o, out);

    dim3 g3(48, B_DIM), b3(256);
    attn_combine<<<g3, b3, 0, stream>>>(P_l, P_o, out);
}

// Round 8
// 192.468 us; speedup vs baseline: 1.0619x; 1.0619x over previous
//
#include <hip/hip_runtime.h>
#include <math.h>

#define B_DIM 4
#define S_DIM 4096
#define E_DIM 1024
#define A_DIM 64
#define M_TOT (B_DIM * S_DIM) /* 16384 */

typedef __bf16 v8bf __attribute__((ext_vector_type(8)));
typedef __bf16 v4bf __attribute__((ext_vector_type(4)));
typedef float  v4f  __attribute__((ext_vector_type(4)));

__device__ __forceinline__ v4f mfma16(v8bf a, v8bf b, v4f c) {
    return __builtin_amdgcn_mfma_f32_16x16x32_bf16(a, b, c, 0, 0, 0);
}

// async global->LDS DMA, 16B per lane.  Dest = wave-uniform base + lane*16.
__device__ __forceinline__ void lds_dma16(const void* g, void* l) {
    __builtin_amdgcn_global_load_lds(
        (const __attribute__((address_space(1))) unsigned int*)g,
        (__attribute__((address_space(3))) unsigned int*)l, 16, 0, 0);
}

// ---------------------------------------------------------------------------
// Pre-pass: fp32 weights -> bf16 Wb[192][1024] (rows 0-63 K, 64-127 Q, 128-191 V).
// ---------------------------------------------------------------------------
__global__ __launch_bounds__(256) void wconv_kernel(
    const float* __restrict__ Wk, const float* __restrict__ Wq,
    const float* __restrict__ Wv, __bf16* __restrict__ Wb)
{
    const int i = blockIdx.x * 256 + threadIdx.x;   // float4 index, 49152 total
    const int w = i >> 14;
    const int off = (i & 16383) * 4;
    const float* s = ((w == 0) ? Wk : (w == 1) ? Wq : Wv) + off;
    float4 v = *(const float4*)s;
    v4bf o;
    o[0] = (__bf16)v.x; o[1] = (__bf16)v.y; o[2] = (__bf16)v.z; o[3] = (__bf16)v.w;
    *(v4bf*)(Wb + (size_t)w * 65536 + off) = o;
}

// ---------------------------------------------------------------------------
// Fused QKV projection v6: N-split + LDS-DMA weight staging.
// 1024 blocks x 256 thr; block = 16 rows x 192 cols, K=1024 in 32-wide chunks.
// Per chunk: weight slab 192x32 bf16 (12 KB) DMA'd to LDS (double-buffered,
// 12 wave-issues of 1 KB); wave w ds_read_b128's its 3 B-frags (2-way bank
// pattern = free); A = 2 register float4 loads (double-buffered, 16 regs).
// No VGPR prefetch for the compiler to destroy.  4 blocks/CU: one block's
// per-barrier DMA drain hides behind the other three blocks' compute.
// ---------------------------------------------------------------------------
__global__ __launch_bounds__(256, 4) void qkv_proj_mfma(
    const float* __restrict__ X,
    const __bf16* __restrict__ Wb,   // [192][1024]
    __bf16* __restrict__ Kb,
    __bf16* __restrict__ Qb,
    __bf16* __restrict__ Vt)
{
    const int r0   = blockIdx.x * 16;
    const int w    = threadIdx.x >> 6;
    const int lane = threadIdx.x & 63;
    const int L    = lane & 15;
    const int quad = lane >> 4;
    const int cbase = w * 48;

    __shared__ __bf16 Bs[2][192 * 32]; // 2 x 12 KB weight slabs, [row][k] 64B rows
    __shared__ float  Tv[16][66];      // V transpose staging, 4.2 KB

    v4f acc[3];
#pragma unroll
    for (int nt = 0; nt < 3; ++nt) acc[nt] = (v4f){0.f, 0.f, 0.f, 0.f};

    // DMA addressing: wave w, issue j -> rows [(w*3+j)*16, +16); lane l ->
    // row_local = l>>2, k8 = (l&3)*8 bf16 (16 B).
    const int dma_row = (lane >> 2);
    const int dma_k8  = (lane & 3) * 8;
    auto stageB = [&](int kc, int buf) {
#pragma unroll
        for (int j = 0; j < 3; ++j) {
            const int row0 = (w * 3 + j) * 16;
            const __bf16* g = Wb + (size_t)(row0 + dma_row) * E_DIM + kc * 32 + dma_k8;
            lds_dma16(g, &Bs[buf][row0 * 32]); // wave-uniform base
        }
    };

    const float* Arow = X + (size_t)(r0 + L) * E_DIM;
    const int kq = quad * 8;
    float4 a0[2], a1[2];
    auto loadA = [&](int kc, float4 a[2]) {
        const float* p = Arow + kc * 32 + kq;
        a[0] = *(const float4*)p;
        a[1] = *(const float4*)(p + 4);
    };
    auto cvtA = [&](const float4 a[2]) -> v8bf {
        v8bf f;
        f[0] = (__bf16)a[0].x; f[1] = (__bf16)a[0].y;
        f[2] = (__bf16)a[0].z; f[3] = (__bf16)a[0].w;
        f[4] = (__bf16)a[1].x; f[5] = (__bf16)a[1].y;
        f[6] = (__bf16)a[1].z; f[7] = (__bf16)a[1].w;
        return f;
    };

    // prologue: stage chunk 0
    stageB(0, 0);
    loadA(0, a0);
    __syncthreads(); // drains DMA -> Bs[0] ready

#pragma unroll 1
    for (int kc = 0; kc < 32; ++kc) {
        const int cur = kc & 1;
        if (kc + 1 < 32) {
            stageB(kc + 1, cur ^ 1);
            if (cur) loadA(kc + 1, a0); else loadA(kc + 1, a1);
        }
        // compute chunk kc
        const v8bf af = cvtA(cur ? a1 : a0);
#pragma unroll
        for (int nt = 0; nt < 3; ++nt) {
            const v8bf bf = *(const v8bf*)&Bs[cur][(cbase + nt * 16 + L) * 32 + kq];
            acc[nt] = mfma16(af, bf, acc[nt]);
        }
        __syncthreads(); // chunk kc+1 DMA complete; buffers safe to rotate
    }

    // write-out: c0 = cbase + nt*16 selects K (<64), Q (<128, x1/8), V (->LDS)
#pragma unroll
    for (int nt = 0; nt < 3; ++nt) {
        const int c0 = cbase + nt * 16; // wave-uniform
        if (c0 < 64) {
#pragma unroll
            for (int r = 0; r < 4; ++r)
                Kb[(size_t)(r0 + quad * 4 + r) * A_DIM + c0 + L] = (__bf16)acc[nt][r];
        } else if (c0 < 128) {
#pragma unroll
            for (int r = 0; r < 4; ++r)
                Qb[(size_t)(r0 + quad * 4 + r) * A_DIM + (c0 - 64) + L] =
                    (__bf16)(acc[nt][r] * 0.125f);
        } else {
#pragma unroll
            for (int r = 0; r < 4; ++r)
                Tv[quad * 4 + r][(c0 - 128) + L] = acc[nt][r];
        }
    }
    __syncthreads();

    // cooperative transposed V write: thread t -> row a = t/4, s-chunk = t%4
    {
        const int batch = r0 >> 12;
        const int s0    = r0 & 4095;
        const int a     = threadIdx.x >> 2;
        const int j4    = threadIdx.x & 3;
        v4bf pk;
#pragma unroll
        for (int j = 0; j < 4; ++j) pk[j] = (__bf16)Tv[j4 * 4 + j][a];
        *(v4bf*)(Vt + (size_t)(batch * 64 + a) * S_DIM + s0 + j4 * 4) = pk;
    }
}

// ---------------------------------------------------------------------------
// Causal flash attention v4 (unchanged): split-K, no-max softmax,
// minimal live registers; acc_o MFMA-only -> AGPRs; Pt wave-private.
// ---------------------------------------------------------------------------
__global__ __launch_bounds__(256, 2) void attn_mfma(
    const __bf16* __restrict__ Qb,
    const __bf16* __restrict__ Kb,
    const __bf16* __restrict__ Vt,
    float* __restrict__ P_l,
    float* __restrict__ P_o,
    float* __restrict__ out)
{
    const int b = blockIdx.y;
    const int x = blockIdx.x;
    int qt, ks;
    if (x < 16)      { qt = x;                    ks = 0; }
    else if (x < 48) { qt = 16 + ((x - 16) >> 1); ks = (x - 16) & 1; }
    else if (x < 96) { int y = x - 48; qt = 32 + y / 3;  ks = y % 3; }
    else             { int y = x - 96; qt = 48 + (y >> 2); ks = y & 3; }
    const int nch = (qt >> 4) + 1;

    const int w    = threadIdx.x >> 6;
    const int lane = threadIdx.x & 63;
    const int L    = lane & 15;
    const int quad = lane >> 4;

    __shared__ __align__(16) char smem[67840];
    __bf16 (*Pt)[64][72]   = (__bf16(*)[64][72])smem;           // loop phase
    float*  red_l          = (float*)smem;                      // combine phase
    float (*red_o)[64][65] = (float(*)[64][65])(smem + 1024);
    float*  invs           = (float*)(smem + 67584);

    v8bf qf[4][2];
#pragma unroll
    for (int ni = 0; ni < 4; ++ni)
#pragma unroll
        for (int ka = 0; ka < 2; ++ka)
            qf[ni][ka] = *(const v8bf*)(Qb +
                (size_t)(b * S_DIM + qt * 64 + ni * 16 + L) * A_DIM + ka * 32 + quad * 8);

    v4f acc_o[4][4];
#pragma unroll
    for (int i = 0; i < 4; ++i)
#pragma unroll
        for (int j = 0; j < 4; ++j) acc_o[i][j] = (v4f){0.f, 0.f, 0.f, 0.f};
    float lrun[4] = {0.f, 0.f, 0.f, 0.f};

    const int kt0   = ks * 16 + w;
    const int ktmax = min(ks * 16 + 15, qt);

    for (int kt = kt0; kt <= ktmax; kt += 4) {
        v8bf kf[4][2];
#pragma unroll
        for (int mi = 0; mi < 4; ++mi)
#pragma unroll
            for (int ka = 0; ka < 2; ++ka)
                kf[mi][ka] = *(const v8bf*)(Kb +
                    (size_t)(b * S_DIM + kt * 64 + mi * 16 + L) * A_DIM + ka * 32 + quad * 8);
        v8bf vf[4][2];
#pragma unroll
        for (int ma = 0; ma < 4; ++ma)
#pragma unroll
            for (int ki = 0; ki < 2; ++ki)
                vf[ma][ki] = *(const v8bf*)(Vt +
                    (size_t)(b * 64 + ma * 16 + L) * S_DIM + kt * 64 + ki * 32 + quad * 8);

        const bool diag = (kt == qt);

#pragma unroll
        for (int ni = 0; ni < 4; ++ni) {
            v4f s[4];
#pragma unroll
            for (int mi = 0; mi < 4; ++mi) s[mi] = (v4f){0.f, 0.f, 0.f, 0.f};
#pragma unroll
            for (int mi = 0; mi < 4; ++mi)
#pragma unroll
                for (int ka = 0; ka < 2; ++ka)
                    s[mi] = mfma16(kf[mi][ka], qf[ni][ka], s[mi]);

            float rs = 0.f;
#pragma unroll
            for (int mi = 0; mi < 4; ++mi) {
                v4bf p4;
#pragma unroll
                for (int r = 0; r < 4; ++r) {
                    const bool masked = diag && (mi * 16 + quad * 4 + r > ni * 16 + L);
                    const float p = masked ? 0.f : __expf(s[mi][r]);
                    rs += p;
                    p4[r] = (__bf16)p;
                }
                *(v4bf*)&Pt[w][ni * 16 + L][mi * 16 + quad * 4] = p4;
            }
            lrun[ni] += rs;
        }

        v8bf pf[4][2];
#pragma unroll
        for (int ni = 0; ni < 4; ++ni)
#pragma unroll
            for (int ki = 0; ki < 2; ++ki)
                pf[ni][ki] = *(const v8bf*)&Pt[w][ni * 16 + L][ki * 32 + quad * 8];
#pragma unroll
        for (int ma = 0; ma < 4; ++ma)
#pragma unroll
            for (int ni = 0; ni < 4; ++ni)
#pragma unroll
                for (int ki = 0; ki < 2; ++ki)
                    acc_o[ma][ni] = mfma16(vf[ma][ki], pf[ni][ki], acc_o[ma][ni]);
    }

#pragma unroll
    for (int ni = 0; ni < 4; ++ni) {
        lrun[ni] += __shfl_xor(lrun[ni], 16, 64);
        lrun[ni] += __shfl_xor(lrun[ni], 32, 64);
    }

    __syncthreads();

    if (quad == 0) {
#pragma unroll
        for (int ni = 0; ni < 4; ++ni)
            red_l[w * 64 + ni * 16 + L] = lrun[ni];
    }
#pragma unroll
    for (int ma = 0; ma < 4; ++ma)
#pragma unroll
        for (int ni = 0; ni < 4; ++ni)
#pragma unroll
            for (int r = 0; r < 4; ++r)
                red_o[w][ma * 16 + quad * 4 + r][ni * 16 + L] = acc_o[ma][ni][r];
    __syncthreads();

    const int pidx = (b * 64 + qt) * 4 + ks;
    if (threadIdx.x < 64) {
        const int q = threadIdx.x;
        const float denom = red_l[0 * 64 + q] + red_l[1 * 64 + q]
                          + red_l[2 * 64 + q] + red_l[3 * 64 + q];
        if (nch == 1) {
            invs[q] = 1.0f / denom;
        } else {
            P_l[(size_t)pidx * 64 + q] = denom;
            invs[q] = 1.0f;
        }
    }
    __syncthreads();

    {
        const int q  = threadIdx.x >> 2;
        const int ac = (threadIdx.x & 3) << 4;
        const float sc = invs[q];
        float* dst = (nch == 1)
            ? out + (size_t)(b * S_DIM + qt * 64 + q) * A_DIM
            : P_o + (size_t)pidx * 4096 + (size_t)q * 64;
#pragma unroll
        for (int i4 = 0; i4 < 4; ++i4) {
            float vv[4];
#pragma unroll
            for (int j = 0; j < 4; ++j) {
                const int a = ac + i4 * 4 + j;
                vv[j] = sc * (red_o[0][a][q] + red_o[1][a][q]
                            + red_o[2][a][q] + red_o[3][a][q]);
            }
            *(float4*)(dst + ac + i4 * 4) = make_float4(vv[0], vv[1], vv[2], vv[3]);
        }
    }
}

// ---------------------------------------------------------------------------
// Combine split-K partials for qt >= 16: out = (sum_c O_c) / (sum_c l_c).
// ---------------------------------------------------------------------------
__global__ __launch_bounds__(256) void attn_combine(
    const float* __restrict__ P_l, const float* __restrict__ P_o,
    float* __restrict__ out)
{
    const int qt  = 16 + blockIdx.x;
    const int b   = blockIdx.y;
    const int nch = (qt >> 4) + 1;
    const int base = (b * 64 + qt) * 4;

    __shared__ float inv_s[64];
    if (threadIdx.x < 64) {
        const int q = threadIdx.x;
        float denom = 0.f;
        for (int c = 0; c < nch; ++c)
            denom += P_l[(size_t)(base + c) * 64 + q];
        inv_s[q] = 1.0f / denom;
    }
    __syncthreads();

    const int q  = threadIdx.x >> 2;
    const int ac = (threadIdx.x & 3) << 4;
    const float inv = inv_s[q];
    float* orow = out + (size_t)(b * S_DIM + qt * 64 + q) * A_DIM;
#pragma unroll
    for (int i4 = 0; i4 < 4; ++i4) {
        float4 acc = make_float4(0.f, 0.f, 0.f, 0.f);
        for (int c = 0; c < nch; ++c) {
            float4 v = *(const float4*)(P_o + (size_t)(base + c) * 4096 +
                                        (size_t)q * 64 + ac + i4 * 4);
            acc.x += v.x; acc.y += v.y; acc.z += v.z; acc.w += v.w;
        }
        acc.x *= inv; acc.y *= inv; acc.z *= inv; acc.w *= inv;
        *(float4*)(orow + ac + i4 * 4) = acc;
    }
}

// ---------------------------------------------------------------------------
extern "C" void kernel_launch(void* const* d_in, const int* in_sizes, int n_in,
                              void* d_out, int out_size, void* d_ws, size_t ws_size,
                              hipStream_t stream)
{
    const float* X  = (const float*)d_in[0];
    const float* Wk = (const float*)d_in[1];
    const float* Wq = (const float*)d_in[2];
    const float* Wv = (const float*)d_in[3];
    float* out = (float*)d_out;

    __bf16* Kb = (__bf16*)d_ws;                     // [16384][64]
    __bf16* Qb = Kb + (size_t)M_TOT * A_DIM;        // [16384][64] (x 1/8)
    __bf16* Vt = Qb + (size_t)M_TOT * A_DIM;        // [256][4096] V^T
    __bf16* Wb = Vt + (size_t)M_TOT * A_DIM;        // [192][1024]
    float*  P_l = (float*)(Wb + 3 * 65536);         // [1024][64]
    float*  P_o = P_l + 65536;                      // [1024][64][64]

    wconv_kernel<<<192, 256, 0, stream>>>(Wk, Wq, Wv, Wb);

    qkv_proj_mfma<<<1024, 256, 0, stream>>>(X, Wb, Kb, Qb, Vt);

    dim3 g2(160, B_DIM), b2(256);
    attn_mfma<<<g2, b2, 0, stream>>>(Qb, Kb, Vt, P_l, P_o, out);

    dim3 g3(48, B_DIM), b3(256);
    attn_combine<<<g3, b3, 0, stream>>>(P_l, P_o, out);
}